// Round 4
// baseline (283.306 us; speedup 1.0000x reference)
//
#include <hip/hip_runtime.h>
#include <hip/hip_bf16.h>

// GCN encoder: 3 layers on N=100000 nodes, E=1250000 edges, 64 features.
// gcn(x) = relu(D^-1/2 (A+I) D^-1/2 (xW) + b)
// Folding: hs = dinv .* (xW);  agg[d] = hs[d] + sum_{s->d} hs[s];
//          next layer's GEMM applies relu(dinv[d]*agg + b) as its pre-transform.
// R1: dst-CSR + gather segmented reduction (no fp32 atomics).
// R2: hierarchical scan.  R3: bucketed 2-phase CSR build.
// R4: bf16 hs, histogram-free slab build, b128 gemm k-loop.
// R5: aggregate half-wave uint gathers; LDS-staged partition; 1024t csr_local.
// R6: aggregate quarter-wave uint2 gathers, 16 edges in flight/wave.
// R7: gemm_fused rewritten on split-bf16 MFMA (fp32-accurate, 4 mfma/tile).
// R8: quarter-wave-per-node aggregate; LDS-staged csr_local; shfl scans.
// R9: fused aggregate+GEMM (agg_gemm): block gathers its 64 rows (R8
//     structure) into an LDS activation tile (pre-transform applied), one
//     barrier, then the split-bf16 MFMA core consumes it. Deletes the B
//     fp32 round-trip (2x ~51MB), 2 kernel launches, and overlaps gather
//     latency with MFMA of co-resident blocks. Numerically identical.

#define WG 256
#define BSHIFT 9                 // 512 nodes per bucket
#define BSIZE  (1 << BSHIFT)
#define BCAP   8192              // pair slots per bucket (mean 6400, sd ~80)
#define PCHUNK 2048              // edges per partition block (8 per thread)
#define WT_LD  72                // transposed-W LDS leading dim (bf16 elems)
#define XS_LD  68                // activation tile leading dim (fp32): frag
                                 // reads land <=2-way (free) on 32 banks

typedef __attribute__((ext_vector_type(8))) short bf16x8;
typedef __attribute__((ext_vector_type(4))) float f32x4;

__device__ __forceinline__ unsigned short f2bf(float f) {
    union { float f; unsigned u; } v; v.f = f;
    unsigned r = v.u + 0x7fffu + ((v.u >> 16) & 1u);   // RNE
    return (unsigned short)(r >> 16);
}
__device__ __forceinline__ float bf2f(unsigned short h) {
    union { unsigned u; float f; } v; v.u = ((unsigned)h) << 16;
    return v.f;
}
__device__ __forceinline__ void acc_bf16x2(float& a, float& b, unsigned u) {
    union { unsigned v; float f; } lo, hi;
    lo.v = u << 16;
    hi.v = u & 0xffff0000u;
    a += lo.f;
    b += hi.f;
}

// cur2[b] = b*BCAP  (write cursor into bucket slab)
__global__ __launch_bounds__(WG) void bcur_init(int* __restrict__ cur2, int nbk) {
    int b = threadIdx.x;
    if (b < nbk) cur2[b] = b * BCAP;
}

// Partition edges by dst-bucket into packed pairs ((dst&511)<<32 | src) in
// fixed per-bucket slabs. LDS histogram -> one global atomic per touched
// bucket -> stage (pair,dest) in LDS in bucket-slot order -> linear output
// loop: consecutive threads write consecutive dests within a bucket run.
__global__ __launch_bounds__(WG) void partition(const int* __restrict__ ei,
                                                int* __restrict__ cur2,
                                                unsigned long long* __restrict__ pairs,
                                                int E) {
    __shared__ int hist[256];
    __shared__ int gbase[256];
    __shared__ int lb[256];
    __shared__ int wsum4[4];
    __shared__ unsigned long long sp[PCHUNK];
    __shared__ int sd[PCHUNK];
    const int t = threadIdx.x;
    const int lane = t & 63;
    const int w = t >> 6;
    const int base = blockIdx.x * PCHUNK;
    const int total = min(PCHUNK, E - base);

    hist[t] = 0;
    __syncthreads();

    int s[8], d[8], r[8];
#pragma unroll
    for (int i = 0; i < 8; i++) {
        int e = base + i * WG + t;           // coalesced
        bool ok = e < E;
        s[i] = ok ? ei[e] : 0;
        d[i] = ok ? ei[E + e] : 0;
        r[i] = ok ? atomicAdd(&hist[d[i] >> BSHIFT], 1) : 0;
        if (!ok) d[i] = -1;
    }
    __syncthreads();

    int hv = hist[t];
    if (hv > 0) gbase[t] = atomicAdd(&cur2[t], hv);
    // exclusive scan of hist -> lb: wave shfl scan + 4-wave fixup
    int sc = hv;
#pragma unroll
    for (int ofs = 1; ofs < 64; ofs <<= 1) {
        int u = __shfl_up(sc, ofs);
        if (lane >= ofs) sc += u;
    }
    if (lane == 63) wsum4[w] = sc;
    __syncthreads();
    if (t == 0) {
        int run = 0;
#pragma unroll
        for (int i = 0; i < 4; i++) { int x = wsum4[i]; wsum4[i] = run; run += x; }
    }
    __syncthreads();
    lb[t] = sc + wsum4[w] - hv;              // exclusive
    __syncthreads();

#pragma unroll
    for (int i = 0; i < 8; i++) {
        if (d[i] >= 0) {
            int b = d[i] >> BSHIFT;
            int slot = lb[b] + r[i];
            sp[slot] = ((unsigned long long)(unsigned)(d[i] & (BSIZE - 1)) << 32) |
                       (unsigned)s[i];
            sd[slot] = gbase[b] + r[i];
        }
    }
    __syncthreads();

    for (int j = t; j < total; j += WG)
        pairs[sd[j]] = sp[j];
}

// Scan bucket totals (cur2[b]-b*BCAP) -> bbase[b] (exclusive); off[N] = E.
__global__ __launch_bounds__(WG) void bsum_scan(const int* __restrict__ cur2,
                                                int* __restrict__ bbase, int nbk,
                                                int* __restrict__ off, int N) {
    __shared__ int sums[WG];
    const int t = threadIdx.x;
    int s = (t < nbk) ? (cur2[t] - t * BCAP) : 0;
    sums[t] = s;
    __syncthreads();
    for (int ofs = 1; ofs < WG; ofs <<= 1) {
        int u = (t >= ofs) ? sums[t - ofs] : 0;
        __syncthreads();
        sums[t] += u;
        __syncthreads();
    }
    if (t < nbk) bbase[t] = sums[t] - s;
    if (t == WG - 1) off[N] = sums[WG - 1];
}

// Per-bucket CSR: stage pairs (<=64KB) + bucket-local csr (32KB) in LDS.
// One global pairs read, LDS hist/scatter, shfl scan (2 barriers),
// fully-coalesced csr write-out. 196 blocks x 1024 threads, 100KB LDS.
__global__ __launch_bounds__(1024) void csr_local(const unsigned long long* __restrict__ pairs,
                                                  const int* __restrict__ cur2,
                                                  const int* __restrict__ bbase,
                                                  int* __restrict__ off,
                                                  float* __restrict__ dinv,
                                                  int* __restrict__ csr, int N) {
    __shared__ unsigned long long sp[BCAP];   // 64 KB staged pairs
    __shared__ int cs[BCAP];                  // 32 KB bucket-local csr
    __shared__ int h[BSIZE];
    __shared__ int cur[BSIZE];
    __shared__ int wsum[8];
    const int b = blockIdx.x;
    const int t = threadIdx.x;
    const int lane = t & 63;
    const int w = t >> 6;
    const int node0 = b << BSHIFT;
    const int nlocal = min(BSIZE, N - node0);
    const int pstart = b * BCAP;
    const int cnt = cur2[b] - pstart;
    const int base = bbase[b];

    if (t < BSIZE) h[t] = 0;
    __syncthreads();

    for (int e = t; e < cnt; e += 1024) {     // only global pairs read
        unsigned long long p = pairs[pstart + e];
        sp[e] = p;
        atomicAdd(&h[(int)(p >> 32)], 1);
    }
    __syncthreads();

    // scan h[0..511]: 8-wave shfl scan + cross-wave fixup
    int myh = (t < BSIZE) ? h[t] : 0;
    int s = myh;
#pragma unroll
    for (int d = 1; d < 64; d <<= 1) {
        int u = __shfl_up(s, d);
        if (lane >= d) s += u;
    }
    if (t < BSIZE && lane == 63) wsum[w] = s;
    __syncthreads();
    if (t == 0) {
        int run = 0;
#pragma unroll
        for (int i = 0; i < 8; i++) { int x = wsum[i]; wsum[i] = run; run += x; }
    }
    __syncthreads();
    if (t < BSIZE) {
        int excl = s + wsum[w] - myh;         // bucket-local exclusive prefix
        cur[t] = excl;
        if (t < nlocal) {
            off[node0 + t] = base + excl;
            dinv[node0 + t] = rsqrtf((float)(myh + 1));
        }
    }
    __syncthreads();

    for (int e = t; e < cnt; e += 1024) {     // LDS scatter
        unsigned long long p = sp[e];
        int pos = atomicAdd(&cur[(int)(p >> 32)], 1);
        cs[pos] = (int)(p & 0xffffffffu);
    }
    __syncthreads();

    for (int j = t; j < cnt; j += 1024)       // coalesced write-out
        csr[base + j] = cs[j];
}

// Fused GEMM via split-bf16 MFMA: out = post( pre(in) @ W )  (layer 1 only:
// in = x from global, pre off).
__global__ __launch_bounds__(WG, 4) void gemm_fused(
    const float* __restrict__ in, const float* __restrict__ W,
    const float* __restrict__ dinv, const float* __restrict__ b_pre, int pre_flag,
    int post_scale, const float* __restrict__ b_post,
    void* __restrict__ out1, int out_bf16, int n_rows)
{
    __shared__ __align__(16) short Wh[64 * WT_LD];
    __shared__ __align__(16) short Wl[64 * WT_LD];

    const int t = threadIdx.x;

    // stage W transposed, split hi/lo bf16 (Wt[j][k], j = output col)
    const float4* W4 = (const float4*)W;
#pragma unroll
    for (int i = 0; i < 4; i++) {
        int q = i * WG + t;              // float4 index, 1024 total
        float4 w = W4[q];
        int base = q * 4;
        int k = base >> 6;
        int j0 = base & 63;
        float wf[4] = {w.x, w.y, w.z, w.w};
#pragma unroll
        for (int e = 0; e < 4; e++) {
            unsigned short h = f2bf(wf[e]);
            Wh[(j0 + e) * WT_LD + k] = (short)h;
            Wl[(j0 + e) * WT_LD + k] = (short)f2bf(wf[e] - bf2f(h));
        }
    }

    const int wid = t >> 6;              // wave 0..3
    const int l = t & 63;
    const int lr = l & 15;
    const int lk = l >> 4;
    const int row0 = blockIdx.x * 64 + wid * 16;
    const int arow = row0 + lr;
    const int srow = (arow < n_rows) ? arow : 0;   // safe row for loads

    // A fragments: 2 k-chunks of 32, pre-transform + hi/lo split
    bf16x8 ah[2], al[2];
    float dv = pre_flag ? dinv[srow] : 0.f;
#pragma unroll
    for (int kc = 0; kc < 2; kc++) {
        const float* p = in + (size_t)srow * 64 + kc * 32 + lk * 8;
        float4 v0 = *(const float4*)p;
        float4 v1 = *(const float4*)(p + 4);
        float vv[8] = {v0.x, v0.y, v0.z, v0.w, v1.x, v1.y, v1.z, v1.w};
        if (pre_flag) {
            const float* bp = b_pre + kc * 32 + lk * 8;
            float4 b0 = *(const float4*)bp;
            float4 b1 = *(const float4*)(bp + 4);
            float bb[8] = {b0.x, b0.y, b0.z, b0.w, b1.x, b1.y, b1.z, b1.w};
#pragma unroll
            for (int e = 0; e < 8; e++)
                vv[e] = fmaxf(fmaf(dv, vv[e], bb[e]), 0.f);
        }
#pragma unroll
        for (int e = 0; e < 8; e++) {
            unsigned short h = f2bf(vv[e]);
            ah[kc][e] = (short)h;
            al[kc][e] = (short)f2bf(vv[e] - bf2f(h));
        }
    }

    __syncthreads();

    f32x4 acc[4] = {};
#pragma unroll
    for (int ct = 0; ct < 4; ct++) {
#pragma unroll
        for (int kc = 0; kc < 2; kc++) {
            const short* ph = &Wh[(ct * 16 + lr) * WT_LD + kc * 32 + lk * 8];
            const short* pl = &Wl[(ct * 16 + lr) * WT_LD + kc * 32 + lk * 8];
            bf16x8 bh = *(const bf16x8*)ph;
            bf16x8 bl = *(const bf16x8*)pl;
            acc[ct] = __builtin_amdgcn_mfma_f32_16x16x32_bf16(ah[kc], bh, acc[ct], 0, 0, 0);
            acc[ct] = __builtin_amdgcn_mfma_f32_16x16x32_bf16(al[kc], bh, acc[ct], 0, 0, 0);
            acc[ct] = __builtin_amdgcn_mfma_f32_16x16x32_bf16(ah[kc], bl, acc[ct], 0, 0, 0);
            acc[ct] = __builtin_amdgcn_mfma_f32_16x16x32_bf16(al[kc], bl, acc[ct], 0, 0, 0);
        }
    }

    // store: D[row = row0 + lk*4 + r][col = ct*16 + lr]  (m89-verified C/D map)
#pragma unroll
    for (int r = 0; r < 4; r++) {
        int orow = row0 + lk * 4 + r;
        if (orow >= n_rows) continue;
        float sc = post_scale ? dinv[orow] : 1.0f;
#pragma unroll
        for (int ct = 0; ct < 4; ct++) {
            float bpv = b_post ? b_post[ct * 16 + lr] : 0.f;
            float o = fmaf(acc[ct][r], sc, bpv);
            if (out_bf16)
                ((unsigned short*)out1)[((size_t)orow << 6) + ct * 16 + lr] = f2bf(o);
            else
                ((float*)out1)[((size_t)orow << 6) + ct * 16 + lr] = o;
        }
    }
}

// Fused aggregate + GEMM (layers 2,3):
//   agg[d]   = A[d] + sum_{s->d} A[s]            (A bf16, fp32 accum)
//   act[d]   = relu(dinv[d]*agg[d] + b_pre)      -> LDS tile (fp32)
//   out[d]   = (post_scale ? dinv[d] : 1) * (act @ W) + b_post
// Gather: quarter-wave (16 lanes x uint2) per node, 4 nodes sequential per
// quarter, 16-deep unrolled edge loop (16 gather loads in flight/wave).
// One barrier, then the split-bf16 MFMA core reads A-frags from the tile.
__global__ __launch_bounds__(WG, 4) void agg_gemm(
    const uint2* __restrict__ A4, const float* __restrict__ W,
    const float* __restrict__ dinv, const float* __restrict__ b_pre,
    int post_scale, const float* __restrict__ b_post,
    void* __restrict__ out1, int out_bf16,
    const int* __restrict__ off, const int* __restrict__ csr, int n_rows)
{
    __shared__ __align__(16) short Wh[64 * WT_LD];
    __shared__ __align__(16) short Wl[64 * WT_LD];
    __shared__ __align__(16) float xs[64 * XS_LD];

    const int t = threadIdx.x;

    // stage W transposed, split hi/lo bf16
    const float4* W4 = (const float4*)W;
#pragma unroll
    for (int i = 0; i < 4; i++) {
        int q = i * WG + t;
        float4 w = W4[q];
        int base = q * 4;
        int k = base >> 6;
        int j0 = base & 63;
        float wf[4] = {w.x, w.y, w.z, w.w};
#pragma unroll
        for (int e = 0; e < 4; e++) {
            unsigned short h = f2bf(wf[e]);
            Wh[(j0 + e) * WT_LD + k] = (short)h;
            Wl[(j0 + e) * WT_LD + k] = (short)f2bf(wf[e] - bf2f(h));
        }
    }

    // ---- gather phase: 16 quarter-waves x 4 nodes = 64 rows ----
    const int l = t & 63;
    const int c = l & 15;            // uint2 col (4 bf16 values)
    const int g = l >> 4;            // quarter within wave
    const int qid = (t >> 6) * 4 + g;    // 0..15
    const int row0 = blockIdx.x * 64;
    const float4 bb = *(const float4*)(b_pre + 4 * c);

#pragma unroll
    for (int i = 0; i < 4; i++) {
        int rloc = qid * 4 + i;
        int node = row0 + rloc;
        bool valid = node < n_rows;
        int nc = valid ? node : n_rows - 1;
        int s0 = off[nc];
        int s1 = valid ? off[nc + 1] : s0;

        uint2 v = A4[((size_t)nc << 4) + c];        // self-loop row
        float4 acc = make_float4(0.f, 0.f, 0.f, 0.f);
        acc_bf16x2(acc.x, acc.y, v.x);
        acc_bf16x2(acc.z, acc.w, v.y);

        for (int p = s0; p < s1; p += 16) {
            const int cnt = min(16, s1 - p);
            int idx = (c < cnt) ? csr[p + c] : 0;   // 16-wide prefetch
#pragma unroll
            for (int k = 0; k < 16; k++) {
                int src = __shfl(idx, (g << 4) + k);
                if (k < cnt) {
                    uint2 wv = A4[((size_t)src << 4) + c];
                    acc_bf16x2(acc.x, acc.y, wv.x);
                    acc_bf16x2(acc.z, acc.w, wv.y);
                }
            }
        }

        float dv = dinv[nc];
        float4 o;
        o.x = fmaxf(fmaf(dv, acc.x, bb.x), 0.f);
        o.y = fmaxf(fmaf(dv, acc.y, bb.y), 0.f);
        o.z = fmaxf(fmaf(dv, acc.z, bb.z), 0.f);
        o.w = fmaxf(fmaf(dv, acc.w, bb.w), 0.f);
        *(float4*)(xs + rloc * XS_LD + 4 * c) = o;
    }

    __syncthreads();

    // ---- MFMA phase (split-bf16, A-frags from xs) ----
    const int wid = t >> 6;
    const int lr = l & 15;
    const int lk = l >> 4;
    const int rw0 = blockIdx.x * 64 + wid * 16;

    bf16x8 ah[2], al[2];
#pragma unroll
    for (int kc = 0; kc < 2; kc++) {
        const float* p = xs + (wid * 16 + lr) * XS_LD + kc * 32 + lk * 8;
        float4 v0 = *(const float4*)p;
        float4 v1 = *(const float4*)(p + 4);
        float vv[8] = {v0.x, v0.y, v0.z, v0.w, v1.x, v1.y, v1.z, v1.w};
#pragma unroll
        for (int e = 0; e < 8; e++) {
            unsigned short h = f2bf(vv[e]);
            ah[kc][e] = (short)h;
            al[kc][e] = (short)f2bf(vv[e] - bf2f(h));
        }
    }

    f32x4 acc[4] = {};
#pragma unroll
    for (int ct = 0; ct < 4; ct++) {
#pragma unroll
        for (int kc = 0; kc < 2; kc++) {
            const short* ph = &Wh[(ct * 16 + lr) * WT_LD + kc * 32 + lk * 8];
            const short* pl = &Wl[(ct * 16 + lr) * WT_LD + kc * 32 + lk * 8];
            bf16x8 bh = *(const bf16x8*)ph;
            bf16x8 bl = *(const bf16x8*)pl;
            acc[ct] = __builtin_amdgcn_mfma_f32_16x16x32_bf16(ah[kc], bh, acc[ct], 0, 0, 0);
            acc[ct] = __builtin_amdgcn_mfma_f32_16x16x32_bf16(al[kc], bh, acc[ct], 0, 0, 0);
            acc[ct] = __builtin_amdgcn_mfma_f32_16x16x32_bf16(ah[kc], bl, acc[ct], 0, 0, 0);
            acc[ct] = __builtin_amdgcn_mfma_f32_16x16x32_bf16(al[kc], bl, acc[ct], 0, 0, 0);
        }
    }

#pragma unroll
    for (int r = 0; r < 4; r++) {
        int orow = rw0 + lk * 4 + r;
        if (orow >= n_rows) continue;
        float sc = post_scale ? dinv[orow] : 1.0f;
#pragma unroll
        for (int ct = 0; ct < 4; ct++) {
            float bpv = b_post ? b_post[ct * 16 + lr] : 0.f;
            float o = fmaf(acc[ct][r], sc, bpv);
            if (out_bf16)
                ((unsigned short*)out1)[((size_t)orow << 6) + ct * 16 + lr] = f2bf(o);
            else
                ((float*)out1)[((size_t)orow << 6) + ct * 16 + lr] = o;
        }
    }
}

extern "C" void kernel_launch(void* const* d_in, const int* in_sizes, int n_in,
                              void* d_out, int out_size, void* d_ws, size_t ws_size,
                              hipStream_t stream) {
    const float* x  = (const float*)d_in[0];
    const int*   ei = (const int*)d_in[1];
    const float* W1 = (const float*)d_in[2];
    const float* b1 = (const float*)d_in[3];
    const float* W2 = (const float*)d_in[4];
    const float* b2 = (const float*)d_in[5];
    const float* W3 = (const float*)d_in[6];
    const float* b3 = (const float*)d_in[7];
    float* out = (float*)d_out;

    const int N = in_sizes[0] / 64;    // 100000
    const int E = in_sizes[1] / 2;     // 1250000
    const int nbk = (N + BSIZE - 1) / BSIZE;        // 196 buckets

    // workspace layout
    int*   off  = (int*)d_ws;                       // N+1
    int*   csr  = off + (N + 1);                    // E
    int*   cur2 = csr + E;                          // 256
    int*   bbase= cur2 + 256;                       // 256
    uintptr_t pa = (uintptr_t)(bbase + 256);
    pa = (pa + 255) & ~(uintptr_t)255;
    float* dinv = (float*)pa;                       // N
    __hip_bfloat16* A  = (__hip_bfloat16*)(dinv + N);        // N*64 bf16 (hs)
    __hip_bfloat16* A2 = A + (size_t)N * 64;                 // N*64 bf16 (hs2)
    unsigned long long* pairs = (unsigned long long*)A2;     // aliased: pairs
        // (nbk*BCAP*8 = 12.85MB) dead before A2 is first written (agg_gemm L2)

    const int gG = (N + 63) / 64;
    const int gP = (E + PCHUNK - 1) / PCHUNK;

    // CSR build (per call; ws re-poisoned every launch)
    bcur_init<<<1,   WG, 0, stream>>>(cur2, nbk);
    partition<<<gP,  WG, 0, stream>>>(ei, cur2, pairs, E);
    bsum_scan<<<1,   WG, 0, stream>>>(cur2, bbase, nbk, off, N);
    csr_local<<<nbk, 1024, 0, stream>>>(pairs, cur2, bbase, off, dinv, csr, N);

    // Layer 1: A = bf16(dinv.*(x@W1))
    gemm_fused<<<gG, WG, 0, stream>>>(x, W1, dinv, nullptr, 0, 1, nullptr, A, 1, N);

    // Layer 2 (fused agg+gemm): A2 = bf16(dinv.*(relu(dinv.*agg(A)+b1)@W2))
    agg_gemm<<<gG, WG, 0, stream>>>((const uint2*)A, W2, dinv, b1, 1, nullptr,
                                    A2, 1, off, csr, N);

    // Layer 3 (fused agg+gemm): out = relu(dinv.*agg(A2)+b2)@W3 + b3 (fp32)
    agg_gemm<<<gG, WG, 0, stream>>>((const uint2*)A2, W3, dinv, b2, 0, b3,
                                    out, 0, off, csr, N);
}

// Round 5
// 224.483 us; speedup vs baseline: 1.2620x; 1.2620x over previous
//
#include <hip/hip_runtime.h>
#include <hip/hip_bf16.h>

// GCN encoder: 3 layers on N=100000 nodes, E=1250000 edges, 64 features.
// gcn(x) = relu(D^-1/2 (A+I) D^-1/2 (xW) + b)
// Folding: hs = dinv .* (xW);  agg[d] = hs[d] + sum_{s->d} hs[s];
//          next layer's GEMM applies relu(dinv[d]*agg + b) as its pre-transform.
// R1..R8: dst-CSR gather reduction, bucketed 2-phase CSR build, bf16 hs,
//         split-bf16 MFMA GEMM (fp32-accurate), quarter-wave aggregate,
//         LDS-staged csr_local, shfl scans.
// R9 (REVERTED): agg+gemm fusion regressed 233->283: barrier serialized on
//         slowest of 64 node-chains, occupancy 4 blocks/CU halved loads in
//         flight. Lesson: both kernels are LATENCY-bound; traffic cuts don't
//         pay, parallelism does.
// R10: aggregate: eighth-wave uint4 gathers (8 lanes x 16B = row), one gather
//      instr serves 8 edge-rows; 32-deep unroll + 4 batched idx loads = one
//      index round-trip per node (P(deg>32) ~ 2e-6). CSR build: pairs packed
//      to 32b (dlocal<<17|src, src<2^17), BSHIFT 9->8: 391 buckets x 256
//      nodes, csr_local 512t/34KB LDS -> 4 blocks/CU, all CUs covered
//      (was 196 blocks @ 100KB = 1 block/CU, half the GPU idle).

#define WG 256
#define BSHIFT 8                 // 256 nodes per bucket
#define BSIZE  (1 << BSHIFT)
#define NBK_MAX 512
#define BCAP   4096              // pair slots per bucket (mean 3200, sd ~57)
#define PCHUNK 2048              // edges per partition block (8 per thread)
#define WT_LD  72                // transposed-W LDS leading dim (bf16 elems)

typedef __attribute__((ext_vector_type(8))) short bf16x8;
typedef __attribute__((ext_vector_type(4))) float f32x4;

__device__ __forceinline__ unsigned short f2bf(float f) {
    union { float f; unsigned u; } v; v.f = f;
    unsigned r = v.u + 0x7fffu + ((v.u >> 16) & 1u);   // RNE
    return (unsigned short)(r >> 16);
}
__device__ __forceinline__ float bf2f(unsigned short h) {
    union { unsigned u; float f; } v; v.u = ((unsigned)h) << 16;
    return v.f;
}
__device__ __forceinline__ void acc_bf16x2(float& a, float& b, unsigned u) {
    union { unsigned v; float f; } lo, hi;
    lo.v = u << 16;
    hi.v = u & 0xffff0000u;
    a += lo.f;
    b += hi.f;
}

// cur2[b] = b*BCAP  (write cursor into bucket slab)
__global__ __launch_bounds__(512) void bcur_init(int* __restrict__ cur2) {
    int b = threadIdx.x;
    cur2[b] = b * BCAP;
}

// Partition edges by dst-bucket into packed pairs ((dst&255)<<17 | src) in
// fixed per-bucket slabs. LDS histogram -> one global atomic per touched
// bucket -> stage (pair,dest) in LDS in bucket-slot order -> linear output
// loop: consecutive threads write consecutive dests within a bucket run.
__global__ __launch_bounds__(WG) void partition(const int* __restrict__ ei,
                                                int* __restrict__ cur2,
                                                unsigned* __restrict__ pairs,
                                                int E) {
    __shared__ int hist[NBK_MAX];
    __shared__ int gbase[NBK_MAX];
    __shared__ int lb[NBK_MAX];
    __shared__ int wsum4[4];
    __shared__ unsigned sp[PCHUNK];
    __shared__ int sd[PCHUNK];
    const int t = threadIdx.x;
    const int lane = t & 63;
    const int w = t >> 6;
    const int base = blockIdx.x * PCHUNK;
    const int total = min(PCHUNK, E - base);

    hist[t] = 0;
    hist[t + 256] = 0;
    __syncthreads();

    int s[8], d[8], r[8];
#pragma unroll
    for (int i = 0; i < 8; i++) {
        int e = base + i * WG + t;           // coalesced
        bool ok = e < E;
        s[i] = ok ? ei[e] : 0;
        d[i] = ok ? ei[E + e] : 0;
        r[i] = ok ? atomicAdd(&hist[d[i] >> BSHIFT], 1) : 0;
        if (!ok) d[i] = -1;
    }
    __syncthreads();

    // per-bucket global base (buckets t and t+256)
    int hv0 = hist[t];
    int hv1 = hist[t + 256];
    if (hv0 > 0) gbase[t] = atomicAdd(&cur2[t], hv0);
    if (hv1 > 0) gbase[t + 256] = atomicAdd(&cur2[t + 256], hv1);

    // exclusive scan of hist[0..511] -> lb: thread t owns pair (2t, 2t+1)
    int a0 = hist[2 * t];
    int a1 = hist[2 * t + 1];
    int ps = a0 + a1;
    int sc = ps;
#pragma unroll
    for (int ofs = 1; ofs < 64; ofs <<= 1) {
        int u = __shfl_up(sc, ofs);
        if (lane >= ofs) sc += u;
    }
    if (lane == 63) wsum4[w] = sc;
    __syncthreads();
    if (t == 0) {
        int run = 0;
#pragma unroll
        for (int i = 0; i < 4; i++) { int x = wsum4[i]; wsum4[i] = run; run += x; }
    }
    __syncthreads();
    int excl = sc + wsum4[w] - ps;
    lb[2 * t] = excl;
    lb[2 * t + 1] = excl + a0;
    __syncthreads();

#pragma unroll
    for (int i = 0; i < 8; i++) {
        if (d[i] >= 0) {
            int b = d[i] >> BSHIFT;
            int slot = lb[b] + r[i];
            sp[slot] = ((unsigned)(d[i] & (BSIZE - 1)) << 17) | (unsigned)s[i];
            sd[slot] = gbase[b] + r[i];
        }
    }
    __syncthreads();

    for (int j = t; j < total; j += WG)
        pairs[sd[j]] = sp[j];
}

// Scan bucket totals (cur2[b]-b*BCAP) -> bbase[b] (exclusive); off[N] = E.
__global__ __launch_bounds__(512) void bsum_scan(const int* __restrict__ cur2,
                                                 int* __restrict__ bbase, int nbk,
                                                 int* __restrict__ off, int N) {
    __shared__ int wsum[8];
    const int t = threadIdx.x;
    const int lane = t & 63;
    const int w = t >> 6;
    int s = (t < nbk) ? (cur2[t] - t * BCAP) : 0;
    int sc = s;
#pragma unroll
    for (int ofs = 1; ofs < 64; ofs <<= 1) {
        int u = __shfl_up(sc, ofs);
        if (lane >= ofs) sc += u;
    }
    if (lane == 63) wsum[w] = sc;
    __syncthreads();
    if (t == 0) {
        int run = 0;
#pragma unroll
        for (int i = 0; i < 8; i++) { int x = wsum[i]; wsum[i] = run; run += x; }
    }
    __syncthreads();
    if (t < nbk) bbase[t] = sc + wsum[w] - s;
    if (t == 511) off[N] = sc + wsum[7];    // total = E
}

// Per-bucket CSR: stage packed pairs (16KB) + bucket-local csr (16KB) in LDS.
// One global pairs read, LDS hist/scatter, shfl scan, coalesced write-out.
// 391 blocks x 512 threads, 34KB LDS -> 4 blocks/CU, all CUs covered.
__global__ __launch_bounds__(512) void csr_local(const unsigned* __restrict__ pairs,
                                                 const int* __restrict__ cur2,
                                                 const int* __restrict__ bbase,
                                                 int* __restrict__ off,
                                                 float* __restrict__ dinv,
                                                 int* __restrict__ csr, int N) {
    __shared__ unsigned sp[BCAP];             // 16 KB staged pairs
    __shared__ int cs[BCAP];                  // 16 KB bucket-local csr
    __shared__ int h[BSIZE];
    __shared__ int cur[BSIZE];
    __shared__ int wsum[4];
    const int b = blockIdx.x;
    const int t = threadIdx.x;
    const int lane = t & 63;
    const int w = t >> 6;
    const int node0 = b << BSHIFT;
    const int nlocal = min(BSIZE, N - node0);
    const int pstart = b * BCAP;
    const int cnt = cur2[b] - pstart;
    const int base = bbase[b];

    if (t < BSIZE) h[t] = 0;
    __syncthreads();

    for (int e = t; e < cnt; e += 512) {      // only global pairs read
        unsigned p = pairs[pstart + e];
        sp[e] = p;
        atomicAdd(&h[p >> 17], 1);
    }
    __syncthreads();

    // scan h[0..255]: waves 0..3 shfl scan + cross-wave fixup
    int myh = (t < BSIZE) ? h[t] : 0;
    int sc = myh;
#pragma unroll
    for (int d = 1; d < 64; d <<= 1) {
        int u = __shfl_up(sc, d);
        if (lane >= d) sc += u;
    }
    if (t < BSIZE && lane == 63) wsum[w] = sc;
    __syncthreads();
    if (t == 0) {
        int run = 0;
#pragma unroll
        for (int i = 0; i < 4; i++) { int x = wsum[i]; wsum[i] = run; run += x; }
    }
    __syncthreads();
    if (t < BSIZE) {
        int excl = sc + wsum[w] - myh;        // bucket-local exclusive prefix
        cur[t] = excl;
        if (t < nlocal) {
            off[node0 + t] = base + excl;
            dinv[node0 + t] = rsqrtf((float)(myh + 1));
        }
    }
    __syncthreads();

    for (int e = t; e < cnt; e += 512) {      // LDS scatter
        unsigned p = sp[e];
        int pos = atomicAdd(&cur[p >> 17], 1);
        cs[pos] = (int)(p & 0x1ffffu);
    }
    __syncthreads();

    for (int j = t; j < cnt; j += 512)        // coalesced write-out
        csr[base + j] = cs[j];
}

// Fused GEMM via split-bf16 MFMA: out = post( pre(in) @ W )
//   pre(v)  = pre_flag ? relu(dinv[row]*v + b_pre[col]) : v
//   post(a) = (post_scale ? dinv[row]*a : a) + (b_post ? b_post[col] : 0)
// Block = 64 rows x 64 cols, 4 waves x 16 rows; A-frags from global with
// pre-transform in fp32, split to bf16 hi/lo; W staged transposed hi/lo in
// LDS; 4 MFMAs per (ct,kc) reproduce fp32 accuracy at matrix-core rate.
__global__ __launch_bounds__(WG, 4) void gemm_fused(
    const float* __restrict__ in, const float* __restrict__ W,
    const float* __restrict__ dinv, const float* __restrict__ b_pre, int pre_flag,
    int post_scale, const float* __restrict__ b_post,
    void* __restrict__ out1, int out_bf16, int n_rows)
{
    __shared__ __align__(16) short Wh[64 * WT_LD];
    __shared__ __align__(16) short Wl[64 * WT_LD];

    const int t = threadIdx.x;

    // stage W transposed, split hi/lo bf16 (Wt[j][k], j = output col)
    const float4* W4 = (const float4*)W;
#pragma unroll
    for (int i = 0; i < 4; i++) {
        int q = i * WG + t;              // float4 index, 1024 total
        float4 w = W4[q];
        int base = q * 4;
        int k = base >> 6;
        int j0 = base & 63;
        float wf[4] = {w.x, w.y, w.z, w.w};
#pragma unroll
        for (int e = 0; e < 4; e++) {
            unsigned short h = f2bf(wf[e]);
            Wh[(j0 + e) * WT_LD + k] = (short)h;
            Wl[(j0 + e) * WT_LD + k] = (short)f2bf(wf[e] - bf2f(h));
        }
    }

    const int wid = t >> 6;              // wave 0..3
    const int l = t & 63;
    const int lr = l & 15;
    const int lk = l >> 4;
    const int row0 = blockIdx.x * 64 + wid * 16;
    const int arow = row0 + lr;
    const int srow = (arow < n_rows) ? arow : 0;   // safe row for loads

    // A fragments: 2 k-chunks of 32, pre-transform + hi/lo split
    bf16x8 ah[2], al[2];
    float dv = pre_flag ? dinv[srow] : 0.f;
#pragma unroll
    for (int kc = 0; kc < 2; kc++) {
        const float* p = in + (size_t)srow * 64 + kc * 32 + lk * 8;
        float4 v0 = *(const float4*)p;
        float4 v1 = *(const float4*)(p + 4);
        float vv[8] = {v0.x, v0.y, v0.z, v0.w, v1.x, v1.y, v1.z, v1.w};
        if (pre_flag) {
            const float* bp = b_pre + kc * 32 + lk * 8;
            float4 b0 = *(const float4*)bp;
            float4 b1 = *(const float4*)(bp + 4);
            float bb[8] = {b0.x, b0.y, b0.z, b0.w, b1.x, b1.y, b1.z, b1.w};
#pragma unroll
            for (int e = 0; e < 8; e++)
                vv[e] = fmaxf(fmaf(dv, vv[e], bb[e]), 0.f);
        }
#pragma unroll
        for (int e = 0; e < 8; e++) {
            unsigned short h = f2bf(vv[e]);
            ah[kc][e] = (short)h;
            al[kc][e] = (short)f2bf(vv[e] - bf2f(h));
        }
    }

    __syncthreads();

    f32x4 acc[4] = {};
#pragma unroll
    for (int ct = 0; ct < 4; ct++) {
#pragma unroll
        for (int kc = 0; kc < 2; kc++) {
            const short* ph = &Wh[(ct * 16 + lr) * WT_LD + kc * 32 + lk * 8];
            const short* pl = &Wl[(ct * 16 + lr) * WT_LD + kc * 32 + lk * 8];
            bf16x8 bh = *(const bf16x8*)ph;
            bf16x8 bl = *(const bf16x8*)pl;
            acc[ct] = __builtin_amdgcn_mfma_f32_16x16x32_bf16(ah[kc], bh, acc[ct], 0, 0, 0);
            acc[ct] = __builtin_amdgcn_mfma_f32_16x16x32_bf16(al[kc], bh, acc[ct], 0, 0, 0);
            acc[ct] = __builtin_amdgcn_mfma_f32_16x16x32_bf16(ah[kc], bl, acc[ct], 0, 0, 0);
            acc[ct] = __builtin_amdgcn_mfma_f32_16x16x32_bf16(al[kc], bl, acc[ct], 0, 0, 0);
        }
    }

    // store: D[row = row0 + lk*4 + r][col = ct*16 + lr]  (m89-verified C/D map)
#pragma unroll
    for (int r = 0; r < 4; r++) {
        int orow = row0 + lk * 4 + r;
        if (orow >= n_rows) continue;
        float sc = post_scale ? dinv[orow] : 1.0f;
#pragma unroll
        for (int ct = 0; ct < 4; ct++) {
            float bpv = b_post ? b_post[ct * 16 + lr] : 0.f;
            float o = fmaf(acc[ct][r], sc, bpv);
            if (out_bf16)
                ((unsigned short*)out1)[((size_t)orow << 6) + ct * 16 + lr] = f2bf(o);
            else
                ((float*)out1)[((size_t)orow << 6) + ct * 16 + lr] = o;
        }
    }
}

// Segmented reduction over dst-CSR: B[d] = A[d] + sum A[csr[e]]  (A is bf16).
// Eighth-wave (8 lanes) per node: lane owns uint4 (8 bf16 cols) of the row,
// one gather instruction covers 8 edge-rows (8 nodes x 8 lanes x 16B).
// 32-deep unrolled edge loop with 4 batched index loads: one index round
// trip per node for deg<=32 (P(deg>32) ~ 2e-6), up to 32 gathers in flight.
// 8 consecutive nodes per wave -> 2KB contiguous wave store.
__global__ __launch_bounds__(WG) void aggregate(
    const uint4* __restrict__ A8, float* __restrict__ B,
    const int* __restrict__ off, const int* __restrict__ csr, int N)
{
    const int t = threadIdx.x;
    const int l = t & 63;
    const int c = l & 7;            // uint4 col (8 bf16 values)
    const int g = l >> 3;           // eighth = node sub-slot
    int node = blockIdx.x * 32 + ((t >> 6) << 3) + g;
    const bool valid = node < N;
    if (!valid) node = N - 1;

    const int s0 = off[node];
    const int s1 = valid ? off[node + 1] : s0;

    uint4 v = A8[((size_t)node << 3) + c];          // self-loop row
    float a0 = 0.f, a1 = 0.f, a2 = 0.f, a3 = 0.f;
    float a4 = 0.f, a5 = 0.f, a6 = 0.f, a7 = 0.f;
    acc_bf16x2(a0, a1, v.x);
    acc_bf16x2(a2, a3, v.y);
    acc_bf16x2(a4, a5, v.z);
    acc_bf16x2(a6, a7, v.w);

    for (int p = s0; p < s1; p += 32) {
        const int rem = s1 - p;
        int idx[4];
#pragma unroll
        for (int q = 0; q < 4; q++)
            idx[q] = (8 * q + c < rem) ? csr[p + 8 * q + c] : 0;  // batched
#pragma unroll
        for (int k = 0; k < 32; k++) {
            int src = __shfl(idx[k >> 3], (g << 3) + (k & 7));
            if (k < rem) {
                uint4 wv = A8[((size_t)src << 3) + c];
                acc_bf16x2(a0, a1, wv.x);
                acc_bf16x2(a2, a3, wv.y);
                acc_bf16x2(a4, a5, wv.z);
                acc_bf16x2(a6, a7, wv.w);
            }
        }
    }

    if (valid) {
        float* bp = B + ((size_t)node << 6) + 8 * c;
        *(float4*)bp       = make_float4(a0, a1, a2, a3);
        *(float4*)(bp + 4) = make_float4(a4, a5, a6, a7);
    }
}

extern "C" void kernel_launch(void* const* d_in, const int* in_sizes, int n_in,
                              void* d_out, int out_size, void* d_ws, size_t ws_size,
                              hipStream_t stream) {
    const float* x  = (const float*)d_in[0];
    const int*   ei = (const int*)d_in[1];
    const float* W1 = (const float*)d_in[2];
    const float* b1 = (const float*)d_in[3];
    const float* W2 = (const float*)d_in[4];
    const float* b2 = (const float*)d_in[5];
    const float* W3 = (const float*)d_in[6];
    const float* b3 = (const float*)d_in[7];
    float* out = (float*)d_out;

    const int N = in_sizes[0] / 64;    // 100000
    const int E = in_sizes[1] / 2;     // 1250000
    const int nbk = (N + BSIZE - 1) / BSIZE;        // 391 buckets

    // workspace layout
    int*   off  = (int*)d_ws;                       // N+1
    int*   csr  = off + (N + 1);                    // E
    int*   cur2 = csr + E;                          // 512
    int*   bbase= cur2 + 512;                       // 512
    uintptr_t pa = (uintptr_t)(bbase + 512);
    pa = (pa + 255) & ~(uintptr_t)255;
    float* dinv = (float*)pa;                       // N
    __hip_bfloat16* A = (__hip_bfloat16*)(dinv + N);// N*64 bf16 (hs)
    float* B    = (float*)(A + (size_t)N * 64);     // N*64 fp32 (agg)
    unsigned* pairs = (unsigned*)B;                 // aliased: dead until agg1
                                                    // nbk*BCAP*4 = 6.4MB <= 25.6MB

    const int gG = (N + 63) / 64;
    const int gA = (N + 31) / 32;
    const int gP = (E + PCHUNK - 1) / PCHUNK;

    // CSR build (per call; ws re-poisoned every launch)
    bcur_init<<<1,   512, 0, stream>>>(cur2);
    partition<<<gP,  WG, 0, stream>>>(ei, cur2, pairs, E);
    bsum_scan<<<1,   512, 0, stream>>>(cur2, bbase, nbk, off, N);
    csr_local<<<nbk, 512, 0, stream>>>(pairs, cur2, bbase, off, dinv, csr, N);

    // Layer 1: A = bf16(dinv.*(x@W1)); B = A[d] + sum A[src]
    gemm_fused<<<gG, WG, 0, stream>>>(x, W1, dinv, nullptr, 0, 1, nullptr, A, 1, N);
    aggregate <<<gA, WG, 0, stream>>>((const uint4*)A, B, off, csr, N);

    // Layer 2: in = B (pre: relu(dinv*v + b1)); A = bf16(dinv.*(h@W2)); B = agg
    gemm_fused<<<gG, WG, 0, stream>>>(B, W2, dinv, b1, 1, 1, nullptr, A, 1, N);
    aggregate <<<gA, WG, 0, stream>>>((const uint4*)A, B, off, csr, N);

    // Layer 3: in = B (pre: relu(dinv*v + b2)); out = h@W3 + b3 (fp32)
    gemm_fused<<<gG, WG, 0, stream>>>(B, W3, dinv, b2, 1, 0, b3, out, 0, N);
}

// Round 6
// 219.450 us; speedup vs baseline: 1.2910x; 1.0229x over previous
//
#include <hip/hip_runtime.h>
#include <hip/hip_bf16.h>

// GCN encoder: 3 layers on N=100000 nodes, E=1250000 edges, 64 features.
// gcn(x) = relu(D^-1/2 (A+I) D^-1/2 (xW) + b)
// Folding: hs = dinv .* (xW);  agg[d] = hs[d] + sum_{s->d} hs[s];
//          next layer's GEMM applies relu(dinv[d]*agg + b) as its pre-transform.
// R1..R8: dst-CSR gather reduction, bucketed 2-phase CSR build, bf16 hs,
//         split-bf16 MFMA GEMM (fp32-accurate), LDS-staged csr_local.
// R9 (REVERTED): agg+gemm fusion regressed (latency-bound kernels: traffic
//         cuts don't pay, parallelism does).
// R10: eighth-wave uint4 aggregate (8 edges/load-instr, 32 in flight);
//      32b packed pairs; BSHIFT 8 (391 buckets, all CUs covered).
// R11: dispatch-count cuts. bcur_init -> hipMemsetAsync (cur2 = counts,
//      slab base = b*BCAP + count). bsum_scan folded into csr_local (each
//      block redundantly shfl-scans the 512 bucket counts: ~2us parallel
//      work vs a dedicated dispatch+drain). partition PCHUNK 3072: 1.5x
//      fewer cursor atomics, longer bucket runs (better store coalescing).

#define WG 256
#define BSHIFT 8                 // 256 nodes per bucket
#define BSIZE  (1 << BSHIFT)
#define NBK_MAX 512
#define BCAP   4096              // pair slots per bucket (mean 3200, sd ~57)
#define PCHUNK 3072              // edges per partition block (12 per thread)
#define WT_LD  72                // transposed-W LDS leading dim (bf16 elems)

typedef __attribute__((ext_vector_type(8))) short bf16x8;
typedef __attribute__((ext_vector_type(4))) float f32x4;

__device__ __forceinline__ unsigned short f2bf(float f) {
    union { float f; unsigned u; } v; v.f = f;
    unsigned r = v.u + 0x7fffu + ((v.u >> 16) & 1u);   // RNE
    return (unsigned short)(r >> 16);
}
__device__ __forceinline__ float bf2f(unsigned short h) {
    union { unsigned u; float f; } v; v.u = ((unsigned)h) << 16;
    return v.f;
}
__device__ __forceinline__ void acc_bf16x2(float& a, float& b, unsigned u) {
    union { unsigned v; float f; } lo, hi;
    lo.v = u << 16;
    hi.v = u & 0xffff0000u;
    a += lo.f;
    b += hi.f;
}

// Partition edges by dst-bucket into packed pairs ((dst&255)<<17 | src) in
// fixed per-bucket slabs. cur2[b] holds the bucket COUNT (memset 0 before);
// slab position = b*BCAP + count. LDS histogram -> one global atomic per
// touched bucket -> stage (pair,dest) in LDS in bucket-slot order -> linear
// output loop: consecutive threads write consecutive dests per bucket run.
__global__ __launch_bounds__(WG) void partition(const int* __restrict__ ei,
                                                int* __restrict__ cur2,
                                                unsigned* __restrict__ pairs,
                                                int E) {
    __shared__ int hist[NBK_MAX];
    __shared__ int gbase[NBK_MAX];
    __shared__ int lb[NBK_MAX];
    __shared__ int wsum4[4];
    __shared__ unsigned sp[PCHUNK];
    __shared__ int sd[PCHUNK];
    const int t = threadIdx.x;
    const int lane = t & 63;
    const int w = t >> 6;
    const int base = blockIdx.x * PCHUNK;
    const int total = min(PCHUNK, E - base);

    hist[t] = 0;
    hist[t + 256] = 0;
    __syncthreads();

    int s[12], d[12], r[12];
#pragma unroll
    for (int i = 0; i < 12; i++) {
        int e = base + i * WG + t;           // coalesced
        bool ok = e < E;
        s[i] = ok ? ei[e] : 0;
        d[i] = ok ? ei[E + e] : 0;
        r[i] = ok ? atomicAdd(&hist[d[i] >> BSHIFT], 1) : 0;
        if (!ok) d[i] = -1;
    }
    __syncthreads();

    // per-bucket global base (buckets t and t+256): slab offset + old count
    int hv0 = hist[t];
    int hv1 = hist[t + 256];
    if (hv0 > 0) gbase[t] = t * BCAP + atomicAdd(&cur2[t], hv0);
    if (hv1 > 0) gbase[t + 256] = (t + 256) * BCAP + atomicAdd(&cur2[t + 256], hv1);

    // exclusive scan of hist[0..511] -> lb: thread t owns pair (2t, 2t+1)
    int a0 = hist[2 * t];
    int a1 = hist[2 * t + 1];
    int ps = a0 + a1;
    int sc = ps;
#pragma unroll
    for (int ofs = 1; ofs < 64; ofs <<= 1) {
        int u = __shfl_up(sc, ofs);
        if (lane >= ofs) sc += u;
    }
    if (lane == 63) wsum4[w] = sc;
    __syncthreads();
    if (t == 0) {
        int run = 0;
#pragma unroll
        for (int i = 0; i < 4; i++) { int x = wsum4[i]; wsum4[i] = run; run += x; }
    }
    __syncthreads();
    int excl = sc + wsum4[w] - ps;
    lb[2 * t] = excl;
    lb[2 * t + 1] = excl + a0;
    __syncthreads();

#pragma unroll
    for (int i = 0; i < 12; i++) {
        if (d[i] >= 0) {
            int b = d[i] >> BSHIFT;
            int slot = lb[b] + r[i];
            sp[slot] = ((unsigned)(d[i] & (BSIZE - 1)) << 17) | (unsigned)s[i];
            sd[slot] = gbase[b] + r[i];
        }
    }
    __syncthreads();

    for (int j = t; j < total; j += WG)
        pairs[sd[j]] = sp[j];
}

// Per-bucket CSR. Entry: every block shfl-scans the 512 bucket counts (cur2)
// to get its own global base (replaces the bsum_scan dispatch; block 0 also
// writes off[N]=E). Then: stage packed pairs (16KB) + bucket-local csr
// (16KB) in LDS, LDS hist/scatter, coalesced write-out. 391 blocks x 512
// threads, ~36KB LDS -> 4 blocks/CU.
__global__ __launch_bounds__(512) void csr_local(const unsigned* __restrict__ pairs,
                                                 const int* __restrict__ cur2,
                                                 int* __restrict__ off,
                                                 float* __restrict__ dinv,
                                                 int* __restrict__ csr,
                                                 int N, int nbk) {
    __shared__ unsigned sp[BCAP];             // 16 KB staged pairs
    __shared__ int cs[BCAP];                  // 16 KB bucket-local csr
    __shared__ int h[BSIZE];
    __shared__ int cur[BSIZE];
    __shared__ int bb[NBK_MAX];               // 2 KB exclusive bucket bases
    __shared__ int wsum8[8];
    __shared__ int wsum4[4];
    const int b = blockIdx.x;
    const int t = threadIdx.x;
    const int lane = t & 63;
    const int w = t >> 6;
    const int node0 = b << BSHIFT;
    const int nlocal = min(BSIZE, N - node0);
    const int pstart = b * BCAP;
    const int cnt = cur2[b];                  // count (memset-0 + atomics)

    // ---- bucket-base scan (all 512 counts), replaces bsum_scan ----
    int cval = (t < nbk) ? cur2[t] : 0;
    int sc2 = cval;
#pragma unroll
    for (int ofs = 1; ofs < 64; ofs <<= 1) {
        int u = __shfl_up(sc2, ofs);
        if (lane >= ofs) sc2 += u;
    }
    if (lane == 63) wsum8[w] = sc2;
    if (t < BSIZE) h[t] = 0;                  // hist init (no extra barrier)
    __syncthreads();
    if (t == 0) {
        int run = 0;
#pragma unroll
        for (int i = 0; i < 8; i++) { int x = wsum8[i]; wsum8[i] = run; run += x; }
    }
    __syncthreads();
    bb[t] = sc2 + wsum8[w] - cval;            // exclusive prefix
    if (b == 0 && t == 511) off[N] = sc2 + wsum8[7];   // total = E
    __syncthreads();
    const int base = bb[b];

    // ---- stage pairs + histogram ----
    for (int e = t; e < cnt; e += 512) {      // only global pairs read
        unsigned p = pairs[pstart + e];
        sp[e] = p;
        atomicAdd(&h[p >> 17], 1);
    }
    __syncthreads();

    // scan h[0..255]: waves 0..3 shfl scan + cross-wave fixup
    int myh = (t < BSIZE) ? h[t] : 0;
    int sc = myh;
#pragma unroll
    for (int d = 1; d < 64; d <<= 1) {
        int u = __shfl_up(sc, d);
        if (lane >= d) sc += u;
    }
    if (t < BSIZE && lane == 63) wsum4[w] = sc;
    __syncthreads();
    if (t == 0) {
        int run = 0;
#pragma unroll
        for (int i = 0; i < 4; i++) { int x = wsum4[i]; wsum4[i] = run; run += x; }
    }
    __syncthreads();
    if (t < BSIZE) {
        int excl = sc + wsum4[w] - myh;       // bucket-local exclusive prefix
        cur[t] = excl;
        if (t < nlocal) {
            off[node0 + t] = base + excl;
            dinv[node0 + t] = rsqrtf((float)(myh + 1));
        }
    }
    __syncthreads();

    for (int e = t; e < cnt; e += 512) {      // LDS scatter
        unsigned p = sp[e];
        int pos = atomicAdd(&cur[p >> 17], 1);
        cs[pos] = (int)(p & 0x1ffffu);
    }
    __syncthreads();

    for (int j = t; j < cnt; j += 512)        // coalesced write-out
        csr[base + j] = cs[j];
}

// Fused GEMM via split-bf16 MFMA: out = post( pre(in) @ W )
//   pre(v)  = pre_flag ? relu(dinv[row]*v + b_pre[col]) : v
//   post(a) = (post_scale ? dinv[row]*a : a) + (b_post ? b_post[col] : 0)
// Block = 64 rows x 64 cols, 4 waves x 16 rows; A-frags from global with
// pre-transform in fp32, split to bf16 hi/lo; W staged transposed hi/lo in
// LDS; 4 MFMAs per (ct,kc) reproduce fp32 accuracy at matrix-core rate.
__global__ __launch_bounds__(WG, 4) void gemm_fused(
    const float* __restrict__ in, const float* __restrict__ W,
    const float* __restrict__ dinv, const float* __restrict__ b_pre, int pre_flag,
    int post_scale, const float* __restrict__ b_post,
    void* __restrict__ out1, int out_bf16, int n_rows)
{
    __shared__ __align__(16) short Wh[64 * WT_LD];
    __shared__ __align__(16) short Wl[64 * WT_LD];

    const int t = threadIdx.x;

    // stage W transposed, split hi/lo bf16 (Wt[j][k], j = output col)
    const float4* W4 = (const float4*)W;
#pragma unroll
    for (int i = 0; i < 4; i++) {
        int q = i * WG + t;              // float4 index, 1024 total
        float4 w = W4[q];
        int base = q * 4;
        int k = base >> 6;
        int j0 = base & 63;
        float wf[4] = {w.x, w.y, w.z, w.w};
#pragma unroll
        for (int e = 0; e < 4; e++) {
            unsigned short h = f2bf(wf[e]);
            Wh[(j0 + e) * WT_LD + k] = (short)h;
            Wl[(j0 + e) * WT_LD + k] = (short)f2bf(wf[e] - bf2f(h));
        }
    }

    const int wid = t >> 6;              // wave 0..3
    const int l = t & 63;
    const int lr = l & 15;
    const int lk = l >> 4;
    const int row0 = blockIdx.x * 64 + wid * 16;
    const int arow = row0 + lr;
    const int srow = (arow < n_rows) ? arow : 0;   // safe row for loads

    // A fragments: 2 k-chunks of 32, pre-transform + hi/lo split
    bf16x8 ah[2], al[2];
    float dv = pre_flag ? dinv[srow] : 0.f;
#pragma unroll
    for (int kc = 0; kc < 2; kc++) {
        const float* p = in + (size_t)srow * 64 + kc * 32 + lk * 8;
        float4 v0 = *(const float4*)p;
        float4 v1 = *(const float4*)(p + 4);
        float vv[8] = {v0.x, v0.y, v0.z, v0.w, v1.x, v1.y, v1.z, v1.w};
        if (pre_flag) {
            const float* bp = b_pre + kc * 32 + lk * 8;
            float4 b0 = *(const float4*)bp;
            float4 b1 = *(const float4*)(bp + 4);
            float bb[8] = {b0.x, b0.y, b0.z, b0.w, b1.x, b1.y, b1.z, b1.w};
#pragma unroll
            for (int e = 0; e < 8; e++)
                vv[e] = fmaxf(fmaf(dv, vv[e], bb[e]), 0.f);
        }
#pragma unroll
        for (int e = 0; e < 8; e++) {
            unsigned short h = f2bf(vv[e]);
            ah[kc][e] = (short)h;
            al[kc][e] = (short)f2bf(vv[e] - bf2f(h));
        }
    }

    __syncthreads();

    f32x4 acc[4] = {};
#pragma unroll
    for (int ct = 0; ct < 4; ct++) {
#pragma unroll
        for (int kc = 0; kc < 2; kc++) {
            const short* ph = &Wh[(ct * 16 + lr) * WT_LD + kc * 32 + lk * 8];
            const short* pl = &Wl[(ct * 16 + lr) * WT_LD + kc * 32 + lk * 8];
            bf16x8 bh = *(const bf16x8*)ph;
            bf16x8 bl = *(const bf16x8*)pl;
            acc[ct] = __builtin_amdgcn_mfma_f32_16x16x32_bf16(ah[kc], bh, acc[ct], 0, 0, 0);
            acc[ct] = __builtin_amdgcn_mfma_f32_16x16x32_bf16(al[kc], bh, acc[ct], 0, 0, 0);
            acc[ct] = __builtin_amdgcn_mfma_f32_16x16x32_bf16(ah[kc], bl, acc[ct], 0, 0, 0);
            acc[ct] = __builtin_amdgcn_mfma_f32_16x16x32_bf16(al[kc], bl, acc[ct], 0, 0, 0);
        }
    }

    // store: D[row = row0 + lk*4 + r][col = ct*16 + lr]  (m89-verified C/D map)
#pragma unroll
    for (int r = 0; r < 4; r++) {
        int orow = row0 + lk * 4 + r;
        if (orow >= n_rows) continue;
        float sc = post_scale ? dinv[orow] : 1.0f;
#pragma unroll
        for (int ct = 0; ct < 4; ct++) {
            float bpv = b_post ? b_post[ct * 16 + lr] : 0.f;
            float o = fmaf(acc[ct][r], sc, bpv);
            if (out_bf16)
                ((unsigned short*)out1)[((size_t)orow << 6) + ct * 16 + lr] = f2bf(o);
            else
                ((float*)out1)[((size_t)orow << 6) + ct * 16 + lr] = o;
        }
    }
}

// Segmented reduction over dst-CSR: B[d] = A[d] + sum A[csr[e]]  (A is bf16).
// Eighth-wave (8 lanes) per node: lane owns uint4 (8 bf16 cols) of the row,
// one gather instruction covers 8 edge-rows. 32-deep unrolled edge loop with
// 4 batched index loads: one index round trip per node for deg<=32
// (P(deg>32) ~ 2e-6), up to 32 gathers in flight. 8 consecutive nodes per
// wave -> 2KB contiguous wave store.
__global__ __launch_bounds__(WG) void aggregate(
    const uint4* __restrict__ A8, float* __restrict__ B,
    const int* __restrict__ off, const int* __restrict__ csr, int N)
{
    const int t = threadIdx.x;
    const int l = t & 63;
    const int c = l & 7;            // uint4 col (8 bf16 values)
    const int g = l >> 3;           // eighth = node sub-slot
    int node = blockIdx.x * 32 + ((t >> 6) << 3) + g;
    const bool valid = node < N;
    if (!valid) node = N - 1;

    const int s0 = off[node];
    const int s1 = valid ? off[node + 1] : s0;

    uint4 v = A8[((size_t)node << 3) + c];          // self-loop row
    float a0 = 0.f, a1 = 0.f, a2 = 0.f, a3 = 0.f;
    float a4 = 0.f, a5 = 0.f, a6 = 0.f, a7 = 0.f;
    acc_bf16x2(a0, a1, v.x);
    acc_bf16x2(a2, a3, v.y);
    acc_bf16x2(a4, a5, v.z);
    acc_bf16x2(a6, a7, v.w);

    for (int p = s0; p < s1; p += 32) {
        const int rem = s1 - p;
        int idx[4];
#pragma unroll
        for (int q = 0; q < 4; q++)
            idx[q] = (8 * q + c < rem) ? csr[p + 8 * q + c] : 0;  // batched
#pragma unroll
        for (int k = 0; k < 32; k++) {
            int src = __shfl(idx[k >> 3], (g << 3) + (k & 7));
            if (k < rem) {
                uint4 wv = A8[((size_t)src << 3) + c];
                acc_bf16x2(a0, a1, wv.x);
                acc_bf16x2(a2, a3, wv.y);
                acc_bf16x2(a4, a5, wv.z);
                acc_bf16x2(a6, a7, wv.w);
            }
        }
    }

    if (valid) {
        float* bp = B + ((size_t)node << 6) + 8 * c;
        *(float4*)bp       = make_float4(a0, a1, a2, a3);
        *(float4*)(bp + 4) = make_float4(a4, a5, a6, a7);
    }
}

extern "C" void kernel_launch(void* const* d_in, const int* in_sizes, int n_in,
                              void* d_out, int out_size, void* d_ws, size_t ws_size,
                              hipStream_t stream) {
    const float* x  = (const float*)d_in[0];
    const int*   ei = (const int*)d_in[1];
    const float* W1 = (const float*)d_in[2];
    const float* b1 = (const float*)d_in[3];
    const float* W2 = (const float*)d_in[4];
    const float* b2 = (const float*)d_in[5];
    const float* W3 = (const float*)d_in[6];
    const float* b3 = (const float*)d_in[7];
    float* out = (float*)d_out;

    const int N = in_sizes[0] / 64;    // 100000
    const int E = in_sizes[1] / 2;     // 1250000
    const int nbk = (N + BSIZE - 1) / BSIZE;        // 391 buckets

    // workspace layout
    int*   off  = (int*)d_ws;                       // N+1
    int*   csr  = off + (N + 1);                    // E
    int*   cur2 = csr + E;                          // 512 (bucket counts)
    uintptr_t pa = (uintptr_t)(cur2 + 512);
    pa = (pa + 255) & ~(uintptr_t)255;
    float* dinv = (float*)pa;                       // N
    __hip_bfloat16* A = (__hip_bfloat16*)(dinv + N);// N*64 bf16 (hs)
    float* B    = (float*)(A + (size_t)N * 64);     // N*64 fp32 (agg)
    unsigned* pairs = (unsigned*)B;                 // aliased: dead until agg1
                                                    // nbk*BCAP*4 = 6.4MB <= 25.6MB

    const int gG = (N + 63) / 64;
    const int gA = (N + 31) / 32;
    const int gP = (E + PCHUNK - 1) / PCHUNK;

    // CSR build (per call; ws re-poisoned every launch)
    hipMemsetAsync(cur2, 0, 512 * sizeof(int), stream);
    partition<<<gP,  WG, 0, stream>>>(ei, cur2, pairs, E);
    csr_local<<<nbk, 512, 0, stream>>>(pairs, cur2, off, dinv, csr, N, nbk);

    // Layer 1: A = bf16(dinv.*(x@W1)); B = A[d] + sum A[src]
    gemm_fused<<<gG, WG, 0, stream>>>(x, W1, dinv, nullptr, 0, 1, nullptr, A, 1, N);
    aggregate <<<gA, WG, 0, stream>>>((const uint4*)A, B, off, csr, N);

    // Layer 2: in = B (pre: relu(dinv*v + b1)); A = bf16(dinv.*(h@W2)); B = agg
    gemm_fused<<<gG, WG, 0, stream>>>(B, W2, dinv, b1, 1, 1, nullptr, A, 1, N);
    aggregate <<<gA, WG, 0, stream>>>((const uint4*)A, B, off, csr, N);

    // Layer 3: in = B (pre: relu(dinv*v + b2)); out = h@W3 + b3 (fp32)
    gemm_fused<<<gG, WG, 0, stream>>>(B, W3, dinv, b2, 1, 0, b3, out, 0, N);
}